// Round 7
// baseline (613.838 us; speedup 1.0000x reference)
//
#include <hip/hip_runtime.h>
#include <hip/hip_bf16.h>

#define BB 128
#define NN 512
#define IND 128
#define LD 64
#define NC 10
#define FL 4
#define ROWS (BB*NN)          // 65536
#define HALF 256              // rows per block (2 blocks per sample)

// workspace layout (float units)
#define OFF_ACC 0                               // 8: [kl, mse, nll, acc, counter,...]
#define OFF_FLG 8                               // 1024 unsigned flags [s][stage][p]
#define OFF_XVEC (OFF_FLG + 1024)               // [128][3][512] f32: vm, vv, zss
#define OFF_XHG  (OFF_XVEC + BB*3*NN)           // [128][64] f32 hg partial (p=1)
#define OFF_XHW  (OFF_XHG + BB*64)              // bf16 [128][2][64][256] hwT halves
#define OFF_GSB  (OFF_XHW + (BB*2*64*HALF)/2)   // bf16 [ROWS][512]
#define WS_NEED ((size_t)(OFF_GSB + (size_t)ROWS*256) * 4)

typedef __attribute__((ext_vector_type(8))) short short8v;
typedef __attribute__((ext_vector_type(4))) float f32x4;

__device__ inline float wave_reduce(float v) {
    #pragma unroll
    for (int m = 32; m; m >>= 1) v += __shfl_xor(v, m, 64);
    return v;
}

__device__ inline short f2bf(float f) {
    unsigned u = __float_as_uint(f);
    u += 0x7fff + ((u >> 16) & 1);      // round-to-nearest-even
    return (short)(u >> 16);
}

__device__ inline float bf2f(short s) {
    return __uint_as_float(((unsigned)(unsigned short)s) << 16);
}

// pair handshake: release(write side) / acquire(read side)
__device__ inline void pair_signal(unsigned* f) {
    __syncthreads();                 // all this block's global writes issued
    __threadfence();                 // device-scope release
    if (threadIdx.x == 0) atomicExch(f, 1u);
}
__device__ inline void pair_wait(unsigned* f) {
    if (threadIdx.x == 0) {
        while (atomicAdd(f, 0u) == 0u) { __builtin_amdgcn_s_sleep(8); }
    }
    __syncthreads();
    __threadfence();                 // acquire: invalidate stale cache
}

__global__ void k_zero(float* __restrict__ accums, unsigned* __restrict__ flg) {
    if (threadIdx.x < 8) accums[threadIdx.x] = 0.f;
    flg[threadIdx.x] = 0u;           // 1024 threads cover all flags
}

// 2 blocks per sample; block handles rows [p*256, p*256+256). 1024 thr = 16 waves.
template<bool BF>
__global__ __launch_bounds__(1024) void k_fused(
    const float* __restrict__ gs, const float* __restrict__ hs,
    const int* __restrict__ labels, const float* __restrict__ eps,
    const float* __restrict__ W_s, const float* __restrict__ b_s,
    const float* __restrict__ W_mu, const float* __restrict__ b_mu,
    const float* __restrict__ W_lv, const float* __restrict__ b_lv,
    const float* __restrict__ W_dec, const float* __restrict__ b_dec,
    const float* __restrict__ W1, const float* __restrict__ b1,
    const float* __restrict__ W2, const float* __restrict__ b2,
    const float* __restrict__ beta, const float* __restrict__ fw,
    const float* __restrict__ fb, const float* __restrict__ fs,
    float* __restrict__ ws_f, unsigned short* __restrict__ gsb,
    float* __restrict__ out)
{
    __shared__ unsigned short s_hwT[64 * 512];   // 64 KB full hwT, XOR-swizzled
    __shared__ unsigned short s_h[HALF * 64];    // 32 KB own-half h (alias sWT in B)
    __shared__ float s_rdeg[HALF];               // own-half rdeg
    __shared__ float s_vm[NN], s_vv[NN];         // full after exchange
    __shared__ float s_zs[NN], s_zss[NN];        // zs own-half used; zss full
    __shared__ float s_red[16 * 68];
    __shared__ float s_fin[48];

    const int tid = threadIdx.x, lane = tid & 63, wid = tid >> 6;
    const int b = blockIdx.x >> 1, p = blockIdx.x & 1;
    const int rbase = p * HALF;

    float* accums = ws_f + OFF_ACC;
    unsigned* flg = (unsigned*)(ws_f + OFF_FLG) + b * 8;   // [stage][p]
    float* xv_vm  = ws_f + OFF_XVEC + (size_t)b * 3 * NN;
    float* xv_vv  = xv_vm + NN;
    float* xv_zss = xv_vm + 2 * NN;
    float* xhg    = ws_f + OFF_XHG + (size_t)b * 64;
    unsigned short* xhw = (unsigned short*)(ws_f + OFF_XHW);

    // ---------- phase A: row sums -> rdeg (own half); bf16 copy of gs ----------
    for (int r = 0; r < 16; ++r) {
        int rowl = wid * 16 + r, rowg = rbase + rowl;
        const float4* gp = (const float4*)(gs + ((size_t)b * NN + rowg) * NN) + lane * 2;
        float4 a = gp[0], c = gp[1];
        float ssum = a.x + a.y + a.z + a.w + c.x + c.y + c.z + c.w;
        ssum = wave_reduce(ssum);
        if (lane == 0) s_rdeg[rowl] = 1.f / ssum;
        if constexpr (BF) {
            short8v v;
            v[0] = f2bf(a.x); v[1] = f2bf(a.y); v[2] = f2bf(a.z); v[3] = f2bf(a.w);
            v[4] = f2bf(c.x); v[5] = f2bf(c.y); v[6] = f2bf(c.z); v[7] = f2bf(c.w);
            *(short8v*)(gsb + ((size_t)b * NN + rowg) * NN + lane * 8) = v;
        }
    }

    // ---------- phase B1: W_s^T bf16 swizzled into sWT (alias of s_h) ----------
    unsigned short* sWT = s_h;   // 64 rows x 128 k, 256 B/row
    {
        const float4* wp = (const float4*)W_s + tid * 2;
        float4 w0 = wp[0], w1 = wp[1];
        int k = tid >> 3, l0 = (tid & 7) * 8;
        float wv[8] = {w0.x, w0.y, w0.z, w0.w, w1.x, w1.y, w1.z, w1.w};
        #pragma unroll
        for (int e = 0; e < 8; ++e) {
            int l = l0 + e;
            int byte = (l * 256 + k * 2) ^ ((l & 7) << 4);
            *(unsigned short*)((char*)sWT + byte) = (unsigned short)f2bf(wv[e]);
        }
    }
    __syncthreads();   // rdeg + sWT ready

    // ---------- phase B2: hwT[l][n] for own n-half via MFMA ----------
    {
        int cq = lane & 15, koq = lane >> 4;
        int n0l = wid * 16;
        f32x4 accB[4] = {};
        #pragma unroll
        for (int kk = 0; kk < 4; ++kk) {
            short8v bf[4];
            #pragma unroll
            for (int lt = 0; lt < 4; ++lt) {
                int l = lt * 16 + cq;
                int byte = (l * 256 + (kk * 32 + koq * 8) * 2) ^ ((l & 7) << 4);
                bf[lt] = *(const short8v*)((char*)sWT + byte);
            }
            int rowg = rbase + n0l + cq;
            const float4* hp = (const float4*)(hs + ((size_t)b * NN + rowg) * IND
                                               + kk * 32 + koq * 8);
            float4 h0 = hp[0], h1 = hp[1];
            short8v a;
            a[0] = f2bf(h0.x); a[1] = f2bf(h0.y); a[2] = f2bf(h0.z); a[3] = f2bf(h0.w);
            a[4] = f2bf(h1.x); a[5] = f2bf(h1.y); a[6] = f2bf(h1.z); a[7] = f2bf(h1.w);
            #pragma unroll
            for (int lt = 0; lt < 4; ++lt)
                accB[lt] = __builtin_amdgcn_mfma_f32_16x16x32_bf16(a, bf[lt], accB[lt], 0, 0, 0);
        }
        __syncthreads();   // done reading sWT before overwriting? (writes go to s_hwT, safe; sync for store order below)
        int r0 = (lane >> 4) * 4;
        #pragma unroll
        for (int lt = 0; lt < 4; ++lt)
            #pragma unroll
            for (int q = 0; q < 4; ++q) {
                int nloc = n0l + r0 + q;
                int ng = rbase + nloc;
                int l = lt * 16 + cq;
                int byte = (l * 1024 + ng * 2) ^ ((l & 7) << 4);
                *(unsigned short*)((char*)s_hwT + byte) =
                    (unsigned short)f2bf(accB[lt][q] * s_rdeg[nloc]);
            }
    }
    __syncthreads();   // own hwT half in LDS

    // ---------- exchange hwT halves ----------
    {
        unsigned short* xhw_my = xhw + ((size_t)(b * 2 + p)) * 64 * HALF;
        int idx = tid * 16, l = idx >> 8, nl = idx & 255;
        int ng = rbase + nl;
        short8v v0 = *(const short8v*)((char*)s_hwT + ((l * 1024 + ng * 2) ^ ((l & 7) << 4)));
        short8v v1 = *(const short8v*)((char*)s_hwT + ((l * 1024 + (ng + 8) * 2) ^ ((l & 7) << 4)));
        *(short8v*)(xhw_my + idx) = v0;
        *(short8v*)(xhw_my + idx + 8) = v1;
    }
    pair_signal(&flg[0 * 2 + p]);
    pair_wait(&flg[0 * 2 + (1 - p)]);
    {
        const unsigned short* xhw_o = xhw + ((size_t)(b * 2 + (1 - p))) * 64 * HALF;
        int idx = tid * 16, l = idx >> 8, nl = idx & 255;
        int ng = (1 - p) * HALF + nl;
        short8v v0 = *(const short8v*)(xhw_o + idx);
        short8v v1 = *(const short8v*)(xhw_o + idx + 8);
        *(short8v*)((char*)s_hwT + ((l * 1024 + ng * 2) ^ ((l & 7) << 4))) = v0;
        *(short8v*)((char*)s_hwT + ((l * 1024 + (ng + 8) * 2) ^ ((l & 7) << 4))) = v1;
    }
    __syncthreads();   // full hwT ready; sWT (s_h) dead

    // ---------- phase C: h(own rows) = relu(g @ hw + b_s) via MFMA ----------
    {
        int cq = lane & 15, koq = lane >> 4;
        int rowl = wid * 16 + cq, rowg = rbase + rowl;
        const unsigned short* A16 = gsb + ((size_t)b * NN + rowg) * NN + koq * 8;
        const float* A32 = gs + ((size_t)b * NN + rowg) * NN + koq * 8;
        f32x4 accC[4] = {};
        for (int kk = 0; kk < 16; ++kk) {
            short8v bf[4];
            #pragma unroll
            for (int lt = 0; lt < 4; ++lt) {
                int l = lt * 16 + cq;
                int byte = (l * 1024 + (kk * 32 + koq * 8) * 2) ^ ((l & 7) << 4);
                bf[lt] = *(const short8v*)((char*)s_hwT + byte);
            }
            short8v a;
            if constexpr (BF) {
                a = *(const short8v*)(A16 + kk * 32);
            } else {
                const float4* gp = (const float4*)(A32 + kk * 32);
                float4 g0 = gp[0], g1 = gp[1];
                a[0] = f2bf(g0.x); a[1] = f2bf(g0.y); a[2] = f2bf(g0.z); a[3] = f2bf(g0.w);
                a[4] = f2bf(g1.x); a[5] = f2bf(g1.y); a[6] = f2bf(g1.z); a[7] = f2bf(g1.w);
            }
            #pragma unroll
            for (int lt = 0; lt < 4; ++lt)
                accC[lt] = __builtin_amdgcn_mfma_f32_16x16x32_bf16(a, bf[lt], accC[lt], 0, 0, 0);
        }
        int r0 = (lane >> 4) * 4;
        float bsv[4];
        #pragma unroll
        for (int lt = 0; lt < 4; ++lt) bsv[lt] = b_s[lt * 16 + cq];
        #pragma unroll
        for (int lt = 0; lt < 4; ++lt)
            #pragma unroll
            for (int q = 0; q < 4; ++q) {
                int nloc = wid * 16 + r0 + q;
                int l = lt * 16 + cq;
                s_h[nloc * 64 + l] = (unsigned short)f2bf(fmaxf(accC[lt][q] + bsv[lt], 0.f));
            }
    }
    __syncthreads();   // own h half ready

    // ---------- phase D1: hm/hv for own rows ----------
    {
        int g16 = tid >> 4, l16 = tid & 15;
        float wmu[4], wlv[4];
        #pragma unroll
        for (int e = 0; e < 4; ++e) { wmu[e] = W_mu[l16 * 4 + e]; wlv[e] = W_lv[l16 * 4 + e]; }
        #pragma unroll
        for (int rr = 0; rr < 4; ++rr) {
            int rowl = g16 * 4 + rr;
            const unsigned short* hp = &s_h[rowl * 64 + l16 * 4];
            float pm = 0.f, pv = 0.f;
            #pragma unroll
            for (int e = 0; e < 4; ++e) {
                float hv = bf2f((short)hp[e]);
                pm += hv * wmu[e]; pv += hv * wlv[e];
            }
            #pragma unroll
            for (int m = 1; m <= 8; m <<= 1) {
                pm += __shfl_xor(pm, m, 64);
                pv += __shfl_xor(pv, m, 64);
            }
            if (l16 == 0) {
                float rd = s_rdeg[rowl];
                int rowg = rbase + rowl;
                float vm = pm * rd, vv = pv * rd;
                s_vm[rowg] = vm; s_vv[rowg] = vv;
                xv_vm[rowg] = vm; xv_vv[rowg] = vv;
            }
        }
    }
    pair_signal(&flg[1 * 2 + p]);
    pair_wait(&flg[1 * 2 + (1 - p)]);
    if (tid < HALF) {
        int rq = (1 - p) * HALF + tid;
        s_vm[rq] = xv_vm[rq];
        s_vv[rq] = xv_vv[rq];
    }
    __syncthreads();

    // ---------- phase D2a: mu_pre/lv_pre for own rows ----------
    {
        float vmr[8], vvr[8];
        #pragma unroll
        for (int e = 0; e < 8; ++e) { vmr[e] = s_vm[lane * 8 + e]; vvr[e] = s_vv[lane * 8 + e]; }
        for (int r = 0; r < 16; ++r) {
            int rowl = wid * 16 + r, rowg = rbase + rowl;
            float sm, sv;
            if constexpr (BF) {
                short8v g8 = *(const short8v*)(gsb + ((size_t)b * NN + rowg) * NN + lane * 8);
                float g0 = bf2f(g8[0]), g1 = bf2f(g8[1]), g2 = bf2f(g8[2]), g3 = bf2f(g8[3]);
                float g4 = bf2f(g8[4]), g5 = bf2f(g8[5]), g6 = bf2f(g8[6]), g7 = bf2f(g8[7]);
                sm = g0*vmr[0]+g1*vmr[1]+g2*vmr[2]+g3*vmr[3]+g4*vmr[4]+g5*vmr[5]+g6*vmr[6]+g7*vmr[7];
                sv = g0*vvr[0]+g1*vvr[1]+g2*vvr[2]+g3*vvr[3]+g4*vvr[4]+g5*vvr[5]+g6*vvr[6]+g7*vvr[7];
            } else {
                const float4* gp = (const float4*)(gs + ((size_t)b * NN + rowg) * NN) + lane * 2;
                float4 ga = gp[0], gc = gp[1];
                sm = ga.x*vmr[0]+ga.y*vmr[1]+ga.z*vmr[2]+ga.w*vmr[3]
                   + gc.x*vmr[4]+gc.y*vmr[5]+gc.z*vmr[6]+gc.w*vmr[7];
                sv = ga.x*vvr[0]+ga.y*vvr[1]+ga.z*vvr[2]+ga.w*vvr[3]
                   + gc.x*vvr[4]+gc.y*vvr[5]+gc.z*vvr[6]+gc.w*vvr[7];
            }
            sm = wave_reduce(sm);
            sv = wave_reduce(sv);
            if (lane == 0) { s_zs[rowg] = sm; s_zss[rowg] = sv; }  // mu_pre / lv_pre
        }
    }
    __syncthreads();

    // ---------- phase D2b: flow for own rows ----------
    float my_kl = 0.f;
    if (tid < HALF) {
        int rowg = rbase + tid;
        float sm = s_zs[rowg], sv = s_zss[rowg];
        float mu = fmaxf(sm + b_mu[0], 0.f);
        float lv = fmaxf(sv + b_lv[0], 0.f);
        float sigma = expf(0.5f * lv);
        float z0 = eps[(size_t)b * NN + rowg] * sigma + mu;
        float z = z0, lj = 0.f;
        #pragma unroll
        for (int k = 0; k < FL; ++k) {
            float tt = tanhf(fw[k] * z + fb[k]);
            float det = 1.f + fs[k] * fw[k] * (1.f - tt * tt);
            lj += logf(fabsf(det) + 1e-7f);
            z += fs[k] * tt;
        }
        float e0 = (z0 - mu) / sigma;
        float logq = -0.5f * e0 * e0 - logf(2.5f * sigma);
        float logp = -0.5f * z * z - logf(2.5f);
        my_kl = logq - lj - logp;
        float zv = 1.f / (1.f + expf(-beta[0] * z));
        float zssv = zv * s_rdeg[tid];
        s_zs[rowg] = zv;
        s_zss[rowg] = zssv;
        xv_zss[rowg] = zssv;
    }
    pair_signal(&flg[2 * 2 + p]);
    pair_wait(&flg[2 * 2 + (1 - p)]);
    if (tid < HALF) {
        int rq = (1 - p) * HALF + tid;
        s_zss[rq] = xv_zss[rq];
    }
    __syncthreads();

    // ---------- phase E: d_pre matvec + mse (own rows) ----------
    float msacc = 0.f;
    {
        float wd = W_dec[lane], bd = b_dec[lane];
        float zr[8];
        #pragma unroll
        for (int e = 0; e < 8; ++e) zr[e] = s_zss[lane * 8 + e];
        for (int r = 0; r < 16; ++r) {
            int rowl = wid * 16 + r, rowg = rbase + rowl;
            float s;
            if constexpr (BF) {
                short8v g8 = *(const short8v*)(gsb + ((size_t)b * NN + rowg) * NN + lane * 8);
                s = bf2f(g8[0])*zr[0]+bf2f(g8[1])*zr[1]+bf2f(g8[2])*zr[2]+bf2f(g8[3])*zr[3]
                  + bf2f(g8[4])*zr[4]+bf2f(g8[5])*zr[5]+bf2f(g8[6])*zr[6]+bf2f(g8[7])*zr[7];
            } else {
                const float4* gp = (const float4*)(gs + ((size_t)b * NN + rowg) * NN) + lane * 2;
                float4 ga = gp[0], gc = gp[1];
                s = ga.x*zr[0]+ga.y*zr[1]+ga.z*zr[2]+ga.w*zr[3]
                  + gc.x*zr[4]+gc.y*zr[5]+gc.z*zr[6]+gc.w*zr[7];
            }
            s = wave_reduce(s);
            float dval = fmaxf(s * wd + bd, 0.f);
            float diff = bf2f((short)s_h[rowl * 64 + lane]) - dval;
            msacc += diff * diff;
        }
    }

    // ---------- phase F: hg partial over own rows ----------
    {
        float acc = 0.f;
        for (int r = 0; r < 16; ++r) {
            int rowl = wid * 16 + r;
            acc += bf2f((short)s_h[rowl * 64 + lane]) * s_zs[rbase + rowl];
        }
        s_red[wid * 68 + lane] = acc;
    }
    {
        float kv = wave_reduce(my_kl);
        float mv = wave_reduce(msacc);
        if (lane == 0) { s_fin[wid] = kv; s_fin[16 + wid] = mv; }
    }
    __syncthreads();

    if (tid == 0) {
        float ksum = 0.f, msum = 0.f;
        #pragma unroll
        for (int w = 0; w < 16; ++w) { ksum += s_fin[w]; msum += s_fin[16 + w]; }
        atomicAdd(&accums[0], ksum);
        atomicAdd(&accums[1], msum);
    }

    float hgv = 0.f;
    if (wid == 0) {
        #pragma unroll
        for (int w = 0; w < 16; ++w) hgv += s_red[w * 68 + lane];
        if (p == 1) xhg[lane] = hgv;
    }
    if (p == 1) {
        pair_signal(&flg[3 * 2 + 1]);
    } else {
        pair_wait(&flg[3 * 2 + 1]);
        if (wid == 0) {
            hgv += xhg[lane];
            s_red[lane] = hgv;
            float x = b1[lane];
            #pragma unroll 8
            for (int k = 0; k < LD; ++k) x += s_red[k] * W1[k * LD + lane];
            x = fmaxf(x, 0.f);
            s_red[256 + lane] = x;
            if (lane < NC) {
                float lg = b2[lane];
                #pragma unroll 8
                for (int k = 0; k < LD; ++k) lg += s_red[256 + k] * W2[k * NC + lane];
                s_fin[32 + lane] = lg;
            }
            if (lane == 0) {
                float mx = s_fin[32]; int pred = 0;
                #pragma unroll
                for (int c = 1; c < NC; ++c) if (s_fin[32 + c] > mx) { mx = s_fin[32 + c]; pred = c; }
                float se = 0.f;
                #pragma unroll
                for (int c = 0; c < NC; ++c) se += expf(s_fin[32 + c] - mx);
                int lab = labels[b];
                atomicAdd(&accums[2], -(s_fin[32 + lab] - (mx + logf(se))));
                if (pred == lab) atomicAdd(&accums[3], 1.0f);
            }
        }
    }

    if (tid == 0) {
        __threadfence();
        unsigned old = atomicAdd((unsigned*)&accums[4], 1u);
        if (old == 2 * BB - 1) {
            float kk = atomicAdd(&accums[0], 0.f);
            float mm = atomicAdd(&accums[1], 0.f);
            float nn = atomicAdd(&accums[2], 0.f);
            float aa = atomicAdd(&accums[3], 0.f);
            out[0] = nn / (float)BB
                   + mm / ((float)BB * NN * LD)
                   + kk / ((float)BB * NN);
            out[1] = aa / (float)BB;
        }
    }
}

extern "C" void kernel_launch(void* const* d_in, const int* in_sizes, int n_in,
                              void* d_out, int out_size, void* d_ws, size_t ws_size,
                              hipStream_t stream) {
    const float* gs    = (const float*)d_in[0];
    const float* hs    = (const float*)d_in[1];
    const int*   labels= (const int*)d_in[2];
    const float* eps   = (const float*)d_in[3];
    const float* W_s   = (const float*)d_in[4];
    const float* b_s   = (const float*)d_in[5];
    const float* W_mu  = (const float*)d_in[6];
    const float* b_mu  = (const float*)d_in[7];
    const float* W_lv  = (const float*)d_in[8];
    const float* b_lv  = (const float*)d_in[9];
    const float* W_dec = (const float*)d_in[10];
    const float* b_dec = (const float*)d_in[11];
    const float* W1    = (const float*)d_in[12];
    const float* b1    = (const float*)d_in[13];
    const float* W2    = (const float*)d_in[14];
    const float* b2    = (const float*)d_in[15];
    const float* beta  = (const float*)d_in[16];
    const float* fw    = (const float*)d_in[17];
    const float* fb    = (const float*)d_in[18];
    const float* fs    = (const float*)d_in[19];

    float* ws = (float*)d_ws;
    unsigned* flg = (unsigned*)(ws + OFF_FLG);
    unsigned short* gsb = (unsigned short*)(ws + OFF_GSB);
    float* out = (float*)d_out;

    k_zero<<<1, 1024, 0, stream>>>(ws + OFF_ACC, flg);
    if (ws_size >= WS_NEED) {
        k_fused<true><<<2 * BB, 1024, 0, stream>>>(gs, hs, labels, eps, W_s, b_s, W_mu, b_mu,
                                                   W_lv, b_lv, W_dec, b_dec, W1, b1, W2, b2,
                                                   beta, fw, fb, fs, ws, gsb, out);
    } else {
        k_fused<false><<<2 * BB, 1024, 0, stream>>>(gs, hs, labels, eps, W_s, b_s, W_mu, b_mu,
                                                    W_lv, b_lv, W_dec, b_dec, W1, b1, W2, b2,
                                                    beta, fw, fb, fs, ws, gsb, out);
    }
}

// Round 8
// 103.629 us; speedup vs baseline: 5.9234x; 5.9234x over previous
//
#include <hip/hip_runtime.h>
#include <hip/hip_bf16.h>

#define BB 128
#define NN 512
#define IND 128
#define LD 64
#define NC 10
#define FL 4
#define ROWS (BB*NN)          // 65536
#define HALF 256              // rows per block in the 2-blocks/sample kernels

// workspace layout (float units)
#define OFF_ACC 0                        // 8: [kl, mse, nll, acc, counter,...]
#define OFF_RDEG (OFF_ACC + 8)           // [ROWS] f32
#define OFF_VM   (OFF_RDEG + ROWS)       // [ROWS] f32
#define OFF_VV   (OFF_VM + ROWS)
#define OFF_ZS   (OFF_VV + ROWS)
#define OFF_ZSS  (OFF_ZS + ROWS)
#define OFF_XHG  (OFF_ZSS + ROWS)        // [BB][2][64] f32
#define OFF_H    (OFF_XHG + BB*128)      // bf16 [ROWS][64] = ROWS*32 floats
#define OFF_GSB  (OFF_H + ROWS*32)       // bf16 [ROWS][512] = ROWS*256 floats
#define WS_NEED ((size_t)(OFF_GSB + (size_t)ROWS*256) * 4)

typedef __attribute__((ext_vector_type(8))) short short8v;
typedef __attribute__((ext_vector_type(4))) float f32x4;

__device__ inline float wave_reduce(float v) {
    #pragma unroll
    for (int m = 32; m; m >>= 1) v += __shfl_xor(v, m, 64);
    return v;
}

__device__ inline short f2bf(float f) {
    unsigned u = __float_as_uint(f);
    u += 0x7fff + ((u >> 16) & 1);      // round-to-nearest-even
    return (short)(u >> 16);
}

__device__ inline float bf2f(short s) {
    return __uint_as_float(((unsigned)(unsigned short)s) << 16);
}

// K1: deg row sums -> rdeg(ws); zero accums; bf16 copy of gs. 4 rows/block.
__global__ __launch_bounds__(256) void k_deg(const float* __restrict__ gs,
                                             float* __restrict__ rdeg,
                                             float* __restrict__ accums,
                                             unsigned short* __restrict__ gsb) {
    if (blockIdx.x == 0 && threadIdx.x < 8) accums[threadIdx.x] = 0.f;
    int t = threadIdx.x;
    int row = blockIdx.x * 4 + (t >> 6), lane = t & 63;
    const float4* r4 = (const float4*)(gs + (size_t)row * NN) + lane * 2;
    float4 a = r4[0], b = r4[1];
    float s = a.x + a.y + a.z + a.w + b.x + b.y + b.z + b.w;
    float sr = wave_reduce(s);
    if (lane == 0) rdeg[row] = 1.0f / sr;
    if (gsb) {
        short8v v;
        v[0] = f2bf(a.x); v[1] = f2bf(a.y); v[2] = f2bf(a.z); v[3] = f2bf(a.w);
        v[4] = f2bf(b.x); v[5] = f2bf(b.y); v[6] = f2bf(b.z); v[7] = f2bf(b.w);
        *(short8v*)(gsb + (size_t)row * NN + lane * 8) = v;
    }
}

// K2: 2 blocks/sample. Full hwT (duplicated, MFMA) -> LDS; C (own 256 rows, MFMA)
// -> h(ws); D1 -> vm/vv(ws). 1024 thr = 16 waves.
template<bool BF>
__global__ __launch_bounds__(1024) void k_hwgemm(
    const float* __restrict__ gs, const unsigned short* __restrict__ gsb,
    const float* __restrict__ hs, const float* __restrict__ W_s,
    const float* __restrict__ b_s, const float* __restrict__ W_mu,
    const float* __restrict__ W_lv, const float* __restrict__ rdeg_ws,
    unsigned short* __restrict__ h_ws, float* __restrict__ vm_ws,
    float* __restrict__ vv_ws)
{
    __shared__ unsigned short s_hwT[64 * 512];   // 64 KB, XOR-swizzled
    __shared__ unsigned short s_h[HALF * 64];    // 32 KB (aliased as sWT in B)
    __shared__ float s_rdeg[NN];

    const int tid = threadIdx.x, lane = tid & 63, wid = tid >> 6;
    const int b = blockIdx.x >> 1, p = blockIdx.x & 1, rbase = p * HALF;

    if (tid < NN) s_rdeg[tid] = rdeg_ws[(size_t)b * NN + tid];

    // ---- B1: W_s^T bf16 swizzled into sWT (alias of s_h) ----
    unsigned short* sWT = s_h;
    {
        const float4* wp = (const float4*)W_s + tid * 2;
        float4 w0 = wp[0], w1 = wp[1];
        int k = tid >> 3, l0 = (tid & 7) * 8;
        float wv[8] = {w0.x, w0.y, w0.z, w0.w, w1.x, w1.y, w1.z, w1.w};
        #pragma unroll
        for (int e = 0; e < 8; ++e) {
            int l = l0 + e;
            int byte = (l * 256 + k * 2) ^ ((l & 7) << 4);
            *(unsigned short*)((char*)sWT + byte) = (unsigned short)f2bf(wv[e]);
        }
    }
    __syncthreads();

    // ---- B2: full hwT[l][n] = bf16(rdeg[n]*(hs@W_s)[n][l]) via MFMA ----
    {
        int n0 = wid * 32, cq = lane & 15, koq = lane >> 4;
        f32x4 accB[2][4] = {};
        #pragma unroll
        for (int kk = 0; kk < 4; ++kk) {
            short8v bf[4];
            #pragma unroll
            for (int lt = 0; lt < 4; ++lt) {
                int l = lt * 16 + cq;
                int byte = (l * 256 + (kk * 32 + koq * 8) * 2) ^ ((l & 7) << 4);
                bf[lt] = *(const short8v*)((char*)sWT + byte);
            }
            #pragma unroll
            for (int nt = 0; nt < 2; ++nt) {
                int row = n0 + nt * 16 + cq;
                const float4* hp = (const float4*)(hs + ((size_t)b * NN + row) * IND
                                                   + kk * 32 + koq * 8);
                float4 h0 = hp[0], h1 = hp[1];
                short8v a;
                a[0] = f2bf(h0.x); a[1] = f2bf(h0.y); a[2] = f2bf(h0.z); a[3] = f2bf(h0.w);
                a[4] = f2bf(h1.x); a[5] = f2bf(h1.y); a[6] = f2bf(h1.z); a[7] = f2bf(h1.w);
                #pragma unroll
                for (int lt = 0; lt < 4; ++lt)
                    accB[nt][lt] = __builtin_amdgcn_mfma_f32_16x16x32_bf16(a, bf[lt], accB[nt][lt], 0, 0, 0);
            }
        }
        __syncthreads();   // all waves done reading sWT before s_h is reused later
        int r0 = (lane >> 4) * 4;
        #pragma unroll
        for (int nt = 0; nt < 2; ++nt)
            #pragma unroll
            for (int lt = 0; lt < 4; ++lt)
                #pragma unroll
                for (int q = 0; q < 4; ++q) {
                    int n = n0 + nt * 16 + r0 + q;
                    int l = lt * 16 + cq;
                    int byte = (l * 1024 + n * 2) ^ ((l & 7) << 4);
                    *(unsigned short*)((char*)s_hwT + byte) =
                        (unsigned short)f2bf(accB[nt][lt][q] * s_rdeg[n]);
                }
    }
    __syncthreads();   // full hwT ready

    // ---- C: h(own rows) = relu(g @ hw + b_s) via MFMA ----
    {
        int cq = lane & 15, koq = lane >> 4;
        int rowl = wid * 16 + cq, rowg = rbase + rowl;
        const unsigned short* A16 = gsb + ((size_t)b * NN + rowg) * NN + koq * 8;
        const float* A32 = gs + ((size_t)b * NN + rowg) * NN + koq * 8;
        f32x4 accC[4] = {};
        for (int kk = 0; kk < 16; ++kk) {
            short8v bf[4];
            #pragma unroll
            for (int lt = 0; lt < 4; ++lt) {
                int l = lt * 16 + cq;
                int byte = (l * 1024 + (kk * 32 + koq * 8) * 2) ^ ((l & 7) << 4);
                bf[lt] = *(const short8v*)((char*)s_hwT + byte);
            }
            short8v a;
            if constexpr (BF) {
                a = *(const short8v*)(A16 + kk * 32);
            } else {
                const float4* gp = (const float4*)(A32 + kk * 32);
                float4 g0 = gp[0], g1 = gp[1];
                a[0] = f2bf(g0.x); a[1] = f2bf(g0.y); a[2] = f2bf(g0.z); a[3] = f2bf(g0.w);
                a[4] = f2bf(g1.x); a[5] = f2bf(g1.y); a[6] = f2bf(g1.z); a[7] = f2bf(g1.w);
            }
            #pragma unroll
            for (int lt = 0; lt < 4; ++lt)
                accC[lt] = __builtin_amdgcn_mfma_f32_16x16x32_bf16(a, bf[lt], accC[lt], 0, 0, 0);
        }
        int r0 = (lane >> 4) * 4;
        float bsv[4];
        #pragma unroll
        for (int lt = 0; lt < 4; ++lt) bsv[lt] = b_s[lt * 16 + cq];
        #pragma unroll
        for (int lt = 0; lt < 4; ++lt)
            #pragma unroll
            for (int q = 0; q < 4; ++q) {
                int nloc = wid * 16 + r0 + q;
                int l = lt * 16 + cq;
                s_h[nloc * 64 + l] = (unsigned short)f2bf(fmaxf(accC[lt][q] + bsv[lt], 0.f));
            }
    }
    __syncthreads();   // own h half ready in LDS

    // ---- dump h -> ws (coalesced) ----
    {
        int rowl = tid >> 2, off = (tid & 3) * 16;
        unsigned short* dst = h_ws + ((size_t)(b * NN + rbase + rowl)) * 64 + off;
        const unsigned short* src = &s_h[rowl * 64 + off];
        *(short8v*)dst = *(const short8v*)src;
        *(short8v*)(dst + 8) = *(const short8v*)(src + 8);
    }

    // ---- D1: vm/vv for own rows -> ws ----
    {
        int g16 = tid >> 4, l16 = tid & 15;
        float wmu[4], wlv[4];
        #pragma unroll
        for (int e = 0; e < 4; ++e) { wmu[e] = W_mu[l16 * 4 + e]; wlv[e] = W_lv[l16 * 4 + e]; }
        #pragma unroll
        for (int rr = 0; rr < 4; ++rr) {
            int rowl = g16 * 4 + rr;
            const unsigned short* hp = &s_h[rowl * 64 + l16 * 4];
            float pm = 0.f, pv = 0.f;
            #pragma unroll
            for (int e = 0; e < 4; ++e) {
                float hv = bf2f((short)hp[e]);
                pm += hv * wmu[e]; pv += hv * wlv[e];
            }
            #pragma unroll
            for (int m = 1; m <= 8; m <<= 1) {
                pm += __shfl_xor(pm, m, 64);
                pv += __shfl_xor(pv, m, 64);
            }
            if (l16 == 0) {
                float rd = s_rdeg[rbase + rowl];
                vm_ws[(size_t)b * NN + rbase + rowl] = pm * rd;
                vv_ws[(size_t)b * NN + rbase + rowl] = pv * rd;
            }
        }
    }
}

// K3: D2a (mu/lv matvec over own rows, full vm/vv) + flow -> zs/zss(ws), kl atomic.
template<bool BF>
__global__ __launch_bounds__(1024) void k_muflow(
    const float* __restrict__ gs, const unsigned short* __restrict__ gsb,
    const float* __restrict__ vm_ws, const float* __restrict__ vv_ws,
    const float* __restrict__ eps, const float* __restrict__ b_mu,
    const float* __restrict__ b_lv, const float* __restrict__ beta,
    const float* __restrict__ fw, const float* __restrict__ fb,
    const float* __restrict__ fs, const float* __restrict__ rdeg_ws,
    float* __restrict__ zs_ws, float* __restrict__ zss_ws,
    float* __restrict__ accums)
{
    __shared__ float s_mp[HALF], s_lp[HALF];
    __shared__ float s_fin[16];
    const int tid = threadIdx.x, lane = tid & 63, wid = tid >> 6;
    const int b = blockIdx.x >> 1, p = blockIdx.x & 1, rbase = p * HALF;

    float vmr[8], vvr[8];
    #pragma unroll
    for (int e = 0; e < 8; ++e) {
        vmr[e] = vm_ws[(size_t)b * NN + lane * 8 + e];
        vvr[e] = vv_ws[(size_t)b * NN + lane * 8 + e];
    }
    for (int r = 0; r < 16; ++r) {
        int rowl = wid * 16 + r, rowg = rbase + rowl;
        float sm, sv;
        if constexpr (BF) {
            short8v g8 = *(const short8v*)(gsb + ((size_t)b * NN + rowg) * NN + lane * 8);
            float g0 = bf2f(g8[0]), g1 = bf2f(g8[1]), g2 = bf2f(g8[2]), g3 = bf2f(g8[3]);
            float g4 = bf2f(g8[4]), g5 = bf2f(g8[5]), g6 = bf2f(g8[6]), g7 = bf2f(g8[7]);
            sm = g0*vmr[0]+g1*vmr[1]+g2*vmr[2]+g3*vmr[3]+g4*vmr[4]+g5*vmr[5]+g6*vmr[6]+g7*vmr[7];
            sv = g0*vvr[0]+g1*vvr[1]+g2*vvr[2]+g3*vvr[3]+g4*vvr[4]+g5*vvr[5]+g6*vvr[6]+g7*vvr[7];
        } else {
            const float4* gp = (const float4*)(gs + ((size_t)b * NN + rowg) * NN) + lane * 2;
            float4 ga = gp[0], gc = gp[1];
            sm = ga.x*vmr[0]+ga.y*vmr[1]+ga.z*vmr[2]+ga.w*vmr[3]
               + gc.x*vmr[4]+gc.y*vmr[5]+gc.z*vmr[6]+gc.w*vmr[7];
            sv = ga.x*vvr[0]+ga.y*vvr[1]+ga.z*vvr[2]+ga.w*vvr[3]
               + gc.x*vvr[4]+gc.y*vvr[5]+gc.z*vvr[6]+gc.w*vvr[7];
        }
        sm = wave_reduce(sm);
        sv = wave_reduce(sv);
        if (lane == 0) { s_mp[rowl] = sm; s_lp[rowl] = sv; }
    }
    __syncthreads();

    float my_kl = 0.f;
    if (tid < HALF) {
        int rowg = rbase + tid;
        float mu = fmaxf(s_mp[tid] + b_mu[0], 0.f);
        float lv = fmaxf(s_lp[tid] + b_lv[0], 0.f);
        float sigma = expf(0.5f * lv);
        float z0 = eps[(size_t)b * NN + rowg] * sigma + mu;
        float z = z0, lj = 0.f;
        #pragma unroll
        for (int k = 0; k < FL; ++k) {
            float tt = tanhf(fw[k] * z + fb[k]);
            float det = 1.f + fs[k] * fw[k] * (1.f - tt * tt);
            lj += logf(fabsf(det) + 1e-7f);
            z += fs[k] * tt;
        }
        float e0 = (z0 - mu) / sigma;
        float logq = -0.5f * e0 * e0 - logf(2.5f * sigma);
        float logp = -0.5f * z * z - logf(2.5f);
        my_kl = logq - lj - logp;
        float zv = 1.f / (1.f + expf(-beta[0] * z));
        float rd = rdeg_ws[(size_t)b * NN + rowg];
        zs_ws[(size_t)b * NN + rowg] = zv;
        zss_ws[(size_t)b * NN + rowg] = zv * rd;
    }
    float kv = wave_reduce(my_kl);
    if (lane == 0) s_fin[wid] = kv;
    __syncthreads();
    if (tid == 0) {
        float ks = 0.f;
        #pragma unroll
        for (int w = 0; w < 16; ++w) ks += s_fin[w];
        atomicAdd(&accums[0], ks);
    }
}

// K4: dec matvec (full zss) + mse atomic + hg partials -> xhg(ws).
template<bool BF>
__global__ __launch_bounds__(1024) void k_dec(
    const float* __restrict__ gs, const unsigned short* __restrict__ gsb,
    const float* __restrict__ zss_ws, const float* __restrict__ zs_ws,
    const unsigned short* __restrict__ h_ws, const float* __restrict__ W_dec,
    const float* __restrict__ b_dec, float* __restrict__ accums,
    float* __restrict__ xhg)
{
    __shared__ float s_zs[HALF];
    __shared__ float s_red[16 * 68];
    __shared__ float s_fin[16];
    const int tid = threadIdx.x, lane = tid & 63, wid = tid >> 6;
    const int b = blockIdx.x >> 1, p = blockIdx.x & 1, rbase = p * HALF;

    if (tid < HALF) s_zs[tid] = zs_ws[(size_t)b * NN + rbase + tid];
    float zr[8];
    #pragma unroll
    for (int e = 0; e < 8; ++e) zr[e] = zss_ws[(size_t)b * NN + lane * 8 + e];
    float wd = W_dec[lane], bd = b_dec[lane];
    __syncthreads();

    float msacc = 0.f, hgacc = 0.f;
    for (int r = 0; r < 16; ++r) {
        int rowl = wid * 16 + r, rowg = rbase + rowl;
        float s;
        if constexpr (BF) {
            short8v g8 = *(const short8v*)(gsb + ((size_t)b * NN + rowg) * NN + lane * 8);
            s = bf2f(g8[0])*zr[0]+bf2f(g8[1])*zr[1]+bf2f(g8[2])*zr[2]+bf2f(g8[3])*zr[3]
              + bf2f(g8[4])*zr[4]+bf2f(g8[5])*zr[5]+bf2f(g8[6])*zr[6]+bf2f(g8[7])*zr[7];
        } else {
            const float4* gp = (const float4*)(gs + ((size_t)b * NN + rowg) * NN) + lane * 2;
            float4 ga = gp[0], gc = gp[1];
            s = ga.x*zr[0]+ga.y*zr[1]+ga.z*zr[2]+ga.w*zr[3]
              + gc.x*zr[4]+gc.y*zr[5]+gc.z*zr[6]+gc.w*zr[7];
        }
        s = wave_reduce(s);
        float dval = fmaxf(s * wd + bd, 0.f);
        float hval = bf2f((short)h_ws[((size_t)b * NN + rowg) * 64 + lane]);
        float diff = hval - dval;
        msacc += diff * diff;
        hgacc += hval * s_zs[rowl];
    }
    s_red[wid * 68 + lane] = hgacc;
    float mv = wave_reduce(msacc);
    if (lane == 0) s_fin[wid] = mv;
    __syncthreads();
    if (tid == 0) {
        float ms = 0.f;
        #pragma unroll
        for (int w = 0; w < 16; ++w) ms += s_fin[w];
        atomicAdd(&accums[1], ms);
    }
    if (wid == 0) {
        float hgv = 0.f;
        #pragma unroll
        for (int w = 0; w < 16; ++w) hgv += s_red[w * 68 + lane];
        xhg[(size_t)b * 128 + p * 64 + lane] = hgv;
    }
}

// K5: classifier per sample + nll/acc atomics + counter finalize -> out.
__global__ __launch_bounds__(64) void k_cls(const float* __restrict__ xhg,
                                            const float* __restrict__ W1,
                                            const float* __restrict__ b1,
                                            const float* __restrict__ W2,
                                            const float* __restrict__ b2,
                                            const int* __restrict__ labels,
                                            float* __restrict__ accums,
                                            float* __restrict__ out)
{
    __shared__ float s_hg[64], s_x[64], s_lg[12];
    int b = blockIdx.x, l = threadIdx.x;
    s_hg[l] = xhg[(size_t)b * 128 + l] + xhg[(size_t)b * 128 + 64 + l];
    __syncthreads();
    float x = b1[l];
    #pragma unroll 8
    for (int k = 0; k < LD; ++k) x += s_hg[k] * W1[k * LD + l];
    s_x[l] = fmaxf(x, 0.f);
    __syncthreads();
    if (l < NC) {
        float lg = b2[l];
        #pragma unroll 8
        for (int k = 0; k < LD; ++k) lg += s_x[k] * W2[k * NC + l];
        s_lg[l] = lg;
    }
    __syncthreads();
    if (l == 0) {
        float mx = s_lg[0]; int pred = 0;
        #pragma unroll
        for (int c = 1; c < NC; ++c) if (s_lg[c] > mx) { mx = s_lg[c]; pred = c; }
        float se = 0.f;
        #pragma unroll
        for (int c = 0; c < NC; ++c) se += expf(s_lg[c] - mx);
        int lab = labels[b];
        atomicAdd(&accums[2], -(s_lg[lab] - (mx + logf(se))));
        if (pred == lab) atomicAdd(&accums[3], 1.0f);
        __threadfence();
        unsigned old = atomicAdd((unsigned*)&accums[4], 1u);
        if (old == BB - 1) {
            float kk = atomicAdd(&accums[0], 0.f);
            float mm = atomicAdd(&accums[1], 0.f);
            float nn = atomicAdd(&accums[2], 0.f);
            float aa = atomicAdd(&accums[3], 0.f);
            out[0] = nn / (float)BB
                   + mm / ((float)BB * NN * LD)
                   + kk / ((float)BB * NN);
            out[1] = aa / (float)BB;
        }
    }
}

extern "C" void kernel_launch(void* const* d_in, const int* in_sizes, int n_in,
                              void* d_out, int out_size, void* d_ws, size_t ws_size,
                              hipStream_t stream) {
    const float* gs    = (const float*)d_in[0];
    const float* hs    = (const float*)d_in[1];
    const int*   labels= (const int*)d_in[2];
    const float* eps   = (const float*)d_in[3];
    const float* W_s   = (const float*)d_in[4];
    const float* b_s   = (const float*)d_in[5];
    const float* W_mu  = (const float*)d_in[6];
    const float* b_mu  = (const float*)d_in[7];
    const float* W_lv  = (const float*)d_in[8];
    const float* b_lv  = (const float*)d_in[9];
    const float* W_dec = (const float*)d_in[10];
    const float* b_dec = (const float*)d_in[11];
    const float* W1    = (const float*)d_in[12];
    const float* b1    = (const float*)d_in[13];
    const float* W2    = (const float*)d_in[14];
    const float* b2    = (const float*)d_in[15];
    const float* beta  = (const float*)d_in[16];
    const float* fw    = (const float*)d_in[17];
    const float* fb    = (const float*)d_in[18];
    const float* fs    = (const float*)d_in[19];

    float* ws      = (float*)d_ws;
    float* accums  = ws + OFF_ACC;
    float* rdeg    = ws + OFF_RDEG;
    float* vm_ws   = ws + OFF_VM;
    float* vv_ws   = ws + OFF_VV;
    float* zs_ws   = ws + OFF_ZS;
    float* zss_ws  = ws + OFF_ZSS;
    float* xhg     = ws + OFF_XHG;
    unsigned short* h_ws = (unsigned short*)(ws + OFF_H);
    unsigned short* gsb  = (unsigned short*)(ws + OFF_GSB);
    float* out = (float*)d_out;

    bool big = ws_size >= WS_NEED;

    k_deg<<<ROWS / 4, 256, 0, stream>>>(gs, rdeg, accums, big ? gsb : nullptr);
    if (big) {
        k_hwgemm<true><<<2 * BB, 1024, 0, stream>>>(gs, gsb, hs, W_s, b_s, W_mu, W_lv,
                                                    rdeg, h_ws, vm_ws, vv_ws);
        k_muflow<true><<<2 * BB, 1024, 0, stream>>>(gs, gsb, vm_ws, vv_ws, eps, b_mu, b_lv,
                                                    beta, fw, fb, fs, rdeg, zs_ws, zss_ws,
                                                    accums);
        k_dec<true><<<2 * BB, 1024, 0, stream>>>(gs, gsb, zss_ws, zs_ws, h_ws, W_dec, b_dec,
                                                 accums, xhg);
    } else {
        k_hwgemm<false><<<2 * BB, 1024, 0, stream>>>(gs, gsb, hs, W_s, b_s, W_mu, W_lv,
                                                     rdeg, h_ws, vm_ws, vv_ws);
        k_muflow<false><<<2 * BB, 1024, 0, stream>>>(gs, gsb, vm_ws, vv_ws, eps, b_mu, b_lv,
                                                     beta, fw, fb, fs, rdeg, zs_ws, zss_ws,
                                                     accums);
        k_dec<false><<<2 * BB, 1024, 0, stream>>>(gs, gsb, zss_ws, zs_ws, h_ws, W_dec, b_dec,
                                                  accums, xhg);
    }
    k_cls<<<BB, 64, 0, stream>>>(xhg, W1, b1, W2, b2, labels, accums, out);
}

// Round 9
// 101.340 us; speedup vs baseline: 6.0572x; 1.0226x over previous
//
#include <hip/hip_runtime.h>
#include <hip/hip_bf16.h>

#define BB 128
#define NN 512
#define IND 128
#define LD 64
#define NC 10
#define FL 4
#define ROWS (BB*NN)          // 65536
#define HALF 256              // rows/block in k_hwgemm (2 blocks/sample)
#define QTR 128               // rows/block in k_muflow/k_dec (4 blocks/sample)

// workspace layout (float units)
#define OFF_ACC 0                        // 8: [kl, mse, nll, acc, counter,...]
#define OFF_RDEG (OFF_ACC + 8)           // [ROWS] f32
#define OFF_VM   (OFF_RDEG + ROWS)
#define OFF_VV   (OFF_VM + ROWS)
#define OFF_ZS   (OFF_VV + ROWS)
#define OFF_ZSS  (OFF_ZS + ROWS)
#define OFF_KLP  (OFF_ZSS + ROWS)        // [512]
#define OFF_MSEP (OFF_KLP + 512)         // [512]
#define OFF_XHG  (OFF_MSEP + 512)        // [BB][4][64] f32
#define OFF_H    (OFF_XHG + BB*256)      // bf16 [ROWS][64] = ROWS*32 floats
#define OFF_GSB  (OFF_H + ROWS*32)       // bf16 [ROWS][512] = ROWS*256 floats
#define WS_NEED ((size_t)(OFF_GSB + (size_t)ROWS*256) * 4)

typedef __attribute__((ext_vector_type(8))) short short8v;
typedef __attribute__((ext_vector_type(4))) float f32x4;

__device__ inline float wave_reduce(float v) {
    #pragma unroll
    for (int m = 32; m; m >>= 1) v += __shfl_xor(v, m, 64);
    return v;
}

__device__ inline short f2bf(float f) {
    unsigned u = __float_as_uint(f);
    u += 0x7fff + ((u >> 16) & 1);      // round-to-nearest-even
    return (short)(u >> 16);
}

__device__ inline float bf2f(short s) {
    return __uint_as_float(((unsigned)(unsigned short)s) << 16);
}

// K1: deg row sums -> rdeg(ws); zero accums; bf16 copy of gs. 4 rows/block.
__global__ __launch_bounds__(256) void k_deg(const float* __restrict__ gs,
                                             float* __restrict__ rdeg,
                                             float* __restrict__ accums,
                                             unsigned short* __restrict__ gsb) {
    if (blockIdx.x == 0 && threadIdx.x < 8) accums[threadIdx.x] = 0.f;
    int t = threadIdx.x;
    int row = blockIdx.x * 4 + (t >> 6), lane = t & 63;
    const float4* r4 = (const float4*)(gs + (size_t)row * NN) + lane * 2;
    float4 a = r4[0], b = r4[1];
    float s = a.x + a.y + a.z + a.w + b.x + b.y + b.z + b.w;
    float sr = wave_reduce(s);
    if (lane == 0) rdeg[row] = 1.0f / sr;
    if (gsb) {
        short8v v;
        v[0] = f2bf(a.x); v[1] = f2bf(a.y); v[2] = f2bf(a.z); v[3] = f2bf(a.w);
        v[4] = f2bf(b.x); v[5] = f2bf(b.y); v[6] = f2bf(b.z); v[7] = f2bf(b.w);
        *(short8v*)(gsb + (size_t)row * NN + lane * 8) = v;
    }
}

// K2: 2 blocks/sample. Full hwT (duplicated, MFMA) -> LDS; C (own 256 rows, MFMA)
// -> h(ws); D1 -> vm/vv(ws). 1024 thr = 16 waves.
template<bool BF>
__global__ __launch_bounds__(1024) void k_hwgemm(
    const float* __restrict__ gs, const unsigned short* __restrict__ gsb,
    const float* __restrict__ hs, const float* __restrict__ W_s,
    const float* __restrict__ b_s, const float* __restrict__ W_mu,
    const float* __restrict__ W_lv, const float* __restrict__ rdeg_ws,
    unsigned short* __restrict__ h_ws, float* __restrict__ vm_ws,
    float* __restrict__ vv_ws)
{
    __shared__ unsigned short s_hwT[64 * 512];   // 64 KB, XOR-swizzled
    __shared__ unsigned short s_h[HALF * 64];    // 32 KB (aliased as sWT in B)
    __shared__ float s_rdeg[NN];

    const int tid = threadIdx.x, lane = tid & 63, wid = tid >> 6;
    const int b = blockIdx.x >> 1, p = blockIdx.x & 1, rbase = p * HALF;

    if (tid < NN) s_rdeg[tid] = rdeg_ws[(size_t)b * NN + tid];

    // ---- B1: W_s^T bf16 swizzled into sWT (alias of s_h) ----
    unsigned short* sWT = s_h;
    {
        const float4* wp = (const float4*)W_s + tid * 2;
        float4 w0 = wp[0], w1 = wp[1];
        int k = tid >> 3, l0 = (tid & 7) * 8;
        float wv[8] = {w0.x, w0.y, w0.z, w0.w, w1.x, w1.y, w1.z, w1.w};
        #pragma unroll
        for (int e = 0; e < 8; ++e) {
            int l = l0 + e;
            int byte = (l * 256 + k * 2) ^ ((l & 7) << 4);
            *(unsigned short*)((char*)sWT + byte) = (unsigned short)f2bf(wv[e]);
        }
    }
    __syncthreads();

    // ---- B2: full hwT[l][n] = bf16(rdeg[n]*(hs@W_s)[n][l]) via MFMA ----
    {
        int n0 = wid * 32, cq = lane & 15, koq = lane >> 4;
        f32x4 accB[2][4] = {};
        #pragma unroll
        for (int kk = 0; kk < 4; ++kk) {
            short8v bf[4];
            #pragma unroll
            for (int lt = 0; lt < 4; ++lt) {
                int l = lt * 16 + cq;
                int byte = (l * 256 + (kk * 32 + koq * 8) * 2) ^ ((l & 7) << 4);
                bf[lt] = *(const short8v*)((char*)sWT + byte);
            }
            #pragma unroll
            for (int nt = 0; nt < 2; ++nt) {
                int row = n0 + nt * 16 + cq;
                const float4* hp = (const float4*)(hs + ((size_t)b * NN + row) * IND
                                                   + kk * 32 + koq * 8);
                float4 h0 = hp[0], h1 = hp[1];
                short8v a;
                a[0] = f2bf(h0.x); a[1] = f2bf(h0.y); a[2] = f2bf(h0.z); a[3] = f2bf(h0.w);
                a[4] = f2bf(h1.x); a[5] = f2bf(h1.y); a[6] = f2bf(h1.z); a[7] = f2bf(h1.w);
                #pragma unroll
                for (int lt = 0; lt < 4; ++lt)
                    accB[nt][lt] = __builtin_amdgcn_mfma_f32_16x16x32_bf16(a, bf[lt], accB[nt][lt], 0, 0, 0);
            }
        }
        __syncthreads();
        int r0 = (lane >> 4) * 4;
        #pragma unroll
        for (int nt = 0; nt < 2; ++nt)
            #pragma unroll
            for (int lt = 0; lt < 4; ++lt)
                #pragma unroll
                for (int q = 0; q < 4; ++q) {
                    int n = n0 + nt * 16 + r0 + q;
                    int l = lt * 16 + cq;
                    int byte = (l * 1024 + n * 2) ^ ((l & 7) << 4);
                    *(unsigned short*)((char*)s_hwT + byte) =
                        (unsigned short)f2bf(accB[nt][lt][q] * s_rdeg[n]);
                }
    }
    __syncthreads();   // full hwT ready

    // ---- C: h(own rows) = relu(g @ hw + b_s) via MFMA ----
    {
        int cq = lane & 15, koq = lane >> 4;
        int rowl = wid * 16 + cq, rowg = rbase + rowl;
        const unsigned short* A16 = gsb + ((size_t)b * NN + rowg) * NN + koq * 8;
        const float* A32 = gs + ((size_t)b * NN + rowg) * NN + koq * 8;
        f32x4 accC[4] = {};
        for (int kk = 0; kk < 16; ++kk) {
            short8v bf[4];
            #pragma unroll
            for (int lt = 0; lt < 4; ++lt) {
                int l = lt * 16 + cq;
                int byte = (l * 1024 + (kk * 32 + koq * 8) * 2) ^ ((l & 7) << 4);
                bf[lt] = *(const short8v*)((char*)s_hwT + byte);
            }
            short8v a;
            if constexpr (BF) {
                a = *(const short8v*)(A16 + kk * 32);
            } else {
                const float4* gp = (const float4*)(A32 + kk * 32);
                float4 g0 = gp[0], g1 = gp[1];
                a[0] = f2bf(g0.x); a[1] = f2bf(g0.y); a[2] = f2bf(g0.z); a[3] = f2bf(g0.w);
                a[4] = f2bf(g1.x); a[5] = f2bf(g1.y); a[6] = f2bf(g1.z); a[7] = f2bf(g1.w);
            }
            #pragma unroll
            for (int lt = 0; lt < 4; ++lt)
                accC[lt] = __builtin_amdgcn_mfma_f32_16x16x32_bf16(a, bf[lt], accC[lt], 0, 0, 0);
        }
        int r0 = (lane >> 4) * 4;
        float bsv[4];
        #pragma unroll
        for (int lt = 0; lt < 4; ++lt) bsv[lt] = b_s[lt * 16 + cq];
        #pragma unroll
        for (int lt = 0; lt < 4; ++lt)
            #pragma unroll
            for (int q = 0; q < 4; ++q) {
                int nloc = wid * 16 + r0 + q;
                int l = lt * 16 + cq;
                s_h[nloc * 64 + l] = (unsigned short)f2bf(fmaxf(accC[lt][q] + bsv[lt], 0.f));
            }
    }
    __syncthreads();

    // ---- dump h -> ws (coalesced) ----
    {
        int rowl = tid >> 2, off = (tid & 3) * 16;
        unsigned short* dst = h_ws + ((size_t)(b * NN + rbase + rowl)) * 64 + off;
        const unsigned short* src = &s_h[rowl * 64 + off];
        *(short8v*)dst = *(const short8v*)src;
        *(short8v*)(dst + 8) = *(const short8v*)(src + 8);
    }

    // ---- D1: vm/vv for own rows -> ws ----
    {
        int g16 = tid >> 4, l16 = tid & 15;
        float wmu[4], wlv[4];
        #pragma unroll
        for (int e = 0; e < 4; ++e) { wmu[e] = W_mu[l16 * 4 + e]; wlv[e] = W_lv[l16 * 4 + e]; }
        #pragma unroll
        for (int rr = 0; rr < 4; ++rr) {
            int rowl = g16 * 4 + rr;
            const unsigned short* hp = &s_h[rowl * 64 + l16 * 4];
            float pm = 0.f, pv = 0.f;
            #pragma unroll
            for (int e = 0; e < 4; ++e) {
                float hv = bf2f((short)hp[e]);
                pm += hv * wmu[e]; pv += hv * wlv[e];
            }
            #pragma unroll
            for (int m = 1; m <= 8; m <<= 1) {
                pm += __shfl_xor(pm, m, 64);
                pv += __shfl_xor(pv, m, 64);
            }
            if (l16 == 0) {
                float rd = s_rdeg[rbase + rowl];
                vm_ws[(size_t)b * NN + rbase + rowl] = pm * rd;
                vv_ws[(size_t)b * NN + rbase + rowl] = pv * rd;
            }
        }
    }
}

// K3: mu/lv matvec via MFMA (B cols: 0=vm, 1=vv, rest 0) + flow.
// 4 blocks/sample, 512 thr = 8 waves, 16 rows/wave.
template<bool BF>
__global__ __launch_bounds__(512) void k_muflow(
    const float* __restrict__ gs, const unsigned short* __restrict__ gsb,
    const float* __restrict__ vm_ws, const float* __restrict__ vv_ws,
    const float* __restrict__ eps, const float* __restrict__ b_mu,
    const float* __restrict__ b_lv, const float* __restrict__ beta,
    const float* __restrict__ fw, const float* __restrict__ fb,
    const float* __restrict__ fs, const float* __restrict__ rdeg_ws,
    float* __restrict__ zs_ws, float* __restrict__ zss_ws,
    float* __restrict__ klp)
{
    __shared__ unsigned short s_bmu[NN], s_blv[NN];
    __shared__ float s_mp[QTR], s_lp[QTR];
    __shared__ float s_fin[8];
    const int tid = threadIdx.x, lane = tid & 63, wid = tid >> 6;
    const int b = blockIdx.x >> 2, qb = blockIdx.x & 3, rbase = qb * QTR;

    if (tid < NN) {
        s_bmu[tid] = (unsigned short)f2bf(vm_ws[(size_t)b * NN + tid]);
        s_blv[tid] = (unsigned short)f2bf(vv_ws[(size_t)b * NN + tid]);
    }
    __syncthreads();

    const int cq = lane & 15, koq = lane >> 4;
    const int rowl = wid * 16 + cq, rowg = rbase + rowl;
    const unsigned short* A16 = gsb + ((size_t)b * NN + rowg) * NN + koq * 8;
    const float* A32 = gs + ((size_t)b * NN + rowg) * NN + koq * 8;
    const char* bptr = (cq == 1) ? (const char*)s_blv : (const char*)s_bmu;
    f32x4 acc = {0.f, 0.f, 0.f, 0.f};
    const short8v bz = {0, 0, 0, 0, 0, 0, 0, 0};
    #pragma unroll 4
    for (int kk = 0; kk < 16; ++kk) {
        short8v a;
        if constexpr (BF) {
            a = *(const short8v*)(A16 + kk * 32);
        } else {
            const float4* gp = (const float4*)(A32 + kk * 32);
            float4 g0 = gp[0], g1 = gp[1];
            a[0] = f2bf(g0.x); a[1] = f2bf(g0.y); a[2] = f2bf(g0.z); a[3] = f2bf(g0.w);
            a[4] = f2bf(g1.x); a[5] = f2bf(g1.y); a[6] = f2bf(g1.z); a[7] = f2bf(g1.w);
        }
        short8v bl = *(const short8v*)(bptr + (kk * 32 + koq * 8) * 2);
        short8v bfrag = (cq < 2) ? bl : bz;
        acc = __builtin_amdgcn_mfma_f32_16x16x32_bf16(a, bfrag, acc, 0, 0, 0);
    }
    int r0 = (lane >> 4) * 4;
    if (cq == 0) {
        #pragma unroll
        for (int q2 = 0; q2 < 4; ++q2) s_mp[wid * 16 + r0 + q2] = acc[q2];
    } else if (cq == 1) {
        #pragma unroll
        for (int q2 = 0; q2 < 4; ++q2) s_lp[wid * 16 + r0 + q2] = acc[q2];
    }
    __syncthreads();

    float my_kl = 0.f;
    if (tid < QTR) {
        int rg = rbase + tid;
        float mu = fmaxf(s_mp[tid] + b_mu[0], 0.f);
        float lv = fmaxf(s_lp[tid] + b_lv[0], 0.f);
        float sigma = expf(0.5f * lv);
        float z0 = eps[(size_t)b * NN + rg] * sigma + mu;
        float z = z0, lj = 0.f;
        #pragma unroll
        for (int k = 0; k < FL; ++k) {
            float tt = tanhf(fw[k] * z + fb[k]);
            float det = 1.f + fs[k] * fw[k] * (1.f - tt * tt);
            lj += logf(fabsf(det) + 1e-7f);
            z += fs[k] * tt;
        }
        float e0 = (z0 - mu) / sigma;
        float logq = -0.5f * e0 * e0 - logf(2.5f * sigma);
        float logp = -0.5f * z * z - logf(2.5f);
        my_kl = logq - lj - logp;
        float zv = 1.f / (1.f + expf(-beta[0] * z));
        float rd = rdeg_ws[(size_t)b * NN + rg];
        zs_ws[(size_t)b * NN + rg] = zv;
        zss_ws[(size_t)b * NN + rg] = zv * rd;
    }
    float kv = wave_reduce(my_kl);
    if (lane == 0) s_fin[wid] = kv;
    __syncthreads();
    if (tid == 0) {
        float ks = 0.f;
        #pragma unroll
        for (int w = 0; w < 8; ++w) ks += s_fin[w];
        klp[blockIdx.x] = ks;
    }
}

// K4: dec matvec via MFMA (B col 0 = zss) + mse/hg epilogue.
// 4 blocks/sample, 512 thr.
template<bool BF>
__global__ __launch_bounds__(512) void k_dec(
    const float* __restrict__ gs, const unsigned short* __restrict__ gsb,
    const float* __restrict__ zss_ws, const float* __restrict__ zs_ws,
    const unsigned short* __restrict__ h_ws, const float* __restrict__ W_dec,
    const float* __restrict__ b_dec, float* __restrict__ msep,
    float* __restrict__ xhg)
{
    __shared__ unsigned short s_bz[NN];
    __shared__ float s_zs[QTR];
    __shared__ float s_dp[QTR];
    __shared__ float s_red[8 * 68];
    __shared__ float s_fin[8];
    const int tid = threadIdx.x, lane = tid & 63, wid = tid >> 6;
    const int b = blockIdx.x >> 2, qb = blockIdx.x & 3, rbase = qb * QTR;

    if (tid < NN) s_bz[tid] = (unsigned short)f2bf(zss_ws[(size_t)b * NN + tid]);
    if (tid < QTR) s_zs[tid] = zs_ws[(size_t)b * NN + rbase + tid];
    __syncthreads();

    const int cq = lane & 15, koq = lane >> 4;
    const int rowl = wid * 16 + cq, rowg = rbase + rowl;
    const unsigned short* A16 = gsb + ((size_t)b * NN + rowg) * NN + koq * 8;
    const float* A32 = gs + ((size_t)b * NN + rowg) * NN + koq * 8;
    f32x4 acc = {0.f, 0.f, 0.f, 0.f};
    const short8v bz = {0, 0, 0, 0, 0, 0, 0, 0};
    #pragma unroll 4
    for (int kk = 0; kk < 16; ++kk) {
        short8v a;
        if constexpr (BF) {
            a = *(const short8v*)(A16 + kk * 32);
        } else {
            const float4* gp = (const float4*)(A32 + kk * 32);
            float4 g0 = gp[0], g1 = gp[1];
            a[0] = f2bf(g0.x); a[1] = f2bf(g0.y); a[2] = f2bf(g0.z); a[3] = f2bf(g0.w);
            a[4] = f2bf(g1.x); a[5] = f2bf(g1.y); a[6] = f2bf(g1.z); a[7] = f2bf(g1.w);
        }
        short8v bl = *(const short8v*)((const char*)s_bz + (kk * 32 + koq * 8) * 2);
        short8v bfrag = (cq == 0) ? bl : bz;
        acc = __builtin_amdgcn_mfma_f32_16x16x32_bf16(a, bfrag, acc, 0, 0, 0);
    }
    int r0 = (lane >> 4) * 4;
    if (cq == 0) {
        #pragma unroll
        for (int q2 = 0; q2 < 4; ++q2) s_dp[wid * 16 + r0 + q2] = acc[q2];
    }
    __syncthreads();

    float wd = W_dec[lane], bd = b_dec[lane];
    float msacc = 0.f, hgacc = 0.f;
    #pragma unroll 4
    for (int r = 0; r < 16; ++r) {
        int rl = wid * 16 + r, rg = rbase + rl;
        float dval = fmaxf(s_dp[rl] * wd + bd, 0.f);
        float hval = bf2f((short)h_ws[((size_t)b * NN + rg) * 64 + lane]);
        float diff = hval - dval;
        msacc += diff * diff;
        hgacc += hval * s_zs[rl];
    }
    s_red[wid * 68 + lane] = hgacc;
    float mv = wave_reduce(msacc);
    if (lane == 0) s_fin[wid] = mv;
    __syncthreads();
    if (tid == 0) {
        float ms = 0.f;
        #pragma unroll
        for (int w = 0; w < 8; ++w) ms += s_fin[w];
        msep[blockIdx.x] = ms;
    }
    if (wid == 0) {
        float hgv = 0.f;
        #pragma unroll
        for (int w = 0; w < 8; ++w) hgv += s_red[w * 68 + lane];
        xhg[(size_t)b * 256 + qb * 64 + lane] = hgv;
    }
}

// K5: classifier per sample + kl/mse partial sums + nll/acc atomics + finalize.
__global__ __launch_bounds__(64) void k_cls(const float* __restrict__ xhg,
                                            const float* __restrict__ klp,
                                            const float* __restrict__ msep,
                                            const float* __restrict__ W1,
                                            const float* __restrict__ b1,
                                            const float* __restrict__ W2,
                                            const float* __restrict__ b2,
                                            const int* __restrict__ labels,
                                            float* __restrict__ accums,
                                            float* __restrict__ out)
{
    __shared__ float s_hg[64], s_x[64], s_lg[12];
    int b = blockIdx.x, l = threadIdx.x;
    s_hg[l] = xhg[(size_t)b * 256 + l] + xhg[(size_t)b * 256 + 64 + l]
            + xhg[(size_t)b * 256 + 128 + l] + xhg[(size_t)b * 256 + 192 + l];
    if (l == 0) atomicAdd(&accums[0], klp[4*b] + klp[4*b+1] + klp[4*b+2] + klp[4*b+3]);
    if (l == 1) atomicAdd(&accums[1], msep[4*b] + msep[4*b+1] + msep[4*b+2] + msep[4*b+3]);
    __syncthreads();
    float x = b1[l];
    #pragma unroll 8
    for (int k = 0; k < LD; ++k) x += s_hg[k] * W1[k * LD + l];
    s_x[l] = fmaxf(x, 0.f);
    __syncthreads();
    if (l < NC) {
        float lg = b2[l];
        #pragma unroll 8
        for (int k = 0; k < LD; ++k) lg += s_x[k] * W2[k * NC + l];
        s_lg[l] = lg;
    }
    __syncthreads();
    if (l == 0) {
        float mx = s_lg[0]; int pred = 0;
        #pragma unroll
        for (int c = 1; c < NC; ++c) if (s_lg[c] > mx) { mx = s_lg[c]; pred = c; }
        float se = 0.f;
        #pragma unroll
        for (int c = 0; c < NC; ++c) se += expf(s_lg[c] - mx);
        int lab = labels[b];
        atomicAdd(&accums[2], -(s_lg[lab] - (mx + logf(se))));
        if (pred == lab) atomicAdd(&accums[3], 1.0f);
        __threadfence();
        unsigned old = atomicAdd((unsigned*)&accums[4], 1u);
        if (old == BB - 1) {
            float kk = atomicAdd(&accums[0], 0.f);
            float mm = atomicAdd(&accums[1], 0.f);
            float nn = atomicAdd(&accums[2], 0.f);
            float aa = atomicAdd(&accums[3], 0.f);
            out[0] = nn / (float)BB
                   + mm / ((float)BB * NN * LD)
                   + kk / ((float)BB * NN);
            out[1] = aa / (float)BB;
        }
    }
}

extern "C" void kernel_launch(void* const* d_in, const int* in_sizes, int n_in,
                              void* d_out, int out_size, void* d_ws, size_t ws_size,
                              hipStream_t stream) {
    const float* gs    = (const float*)d_in[0];
    const float* hs    = (const float*)d_in[1];
    const int*   labels= (const int*)d_in[2];
    const float* eps   = (const float*)d_in[3];
    const float* W_s   = (const float*)d_in[4];
    const float* b_s   = (const float*)d_in[5];
    const float* W_mu  = (const float*)d_in[6];
    const float* b_mu  = (const float*)d_in[7];
    const float* W_lv  = (const float*)d_in[8];
    const float* b_lv  = (const float*)d_in[9];
    const float* W_dec = (const float*)d_in[10];
    const float* b_dec = (const float*)d_in[11];
    const float* W1    = (const float*)d_in[12];
    const float* b1    = (const float*)d_in[13];
    const float* W2    = (const float*)d_in[14];
    const float* b2    = (const float*)d_in[15];
    const float* beta  = (const float*)d_in[16];
    const float* fw    = (const float*)d_in[17];
    const float* fb    = (const float*)d_in[18];
    const float* fs    = (const float*)d_in[19];

    float* ws      = (float*)d_ws;
    float* accums  = ws + OFF_ACC;
    float* rdeg    = ws + OFF_RDEG;
    float* vm_ws   = ws + OFF_VM;
    float* vv_ws   = ws + OFF_VV;
    float* zs_ws   = ws + OFF_ZS;
    float* zss_ws  = ws + OFF_ZSS;
    float* klp     = ws + OFF_KLP;
    float* msep    = ws + OFF_MSEP;
    float* xhg     = ws + OFF_XHG;
    unsigned short* h_ws = (unsigned short*)(ws + OFF_H);
    unsigned short* gsb  = (unsigned short*)(ws + OFF_GSB);
    float* out = (float*)d_out;

    bool big = ws_size >= WS_NEED;

    k_deg<<<ROWS / 4, 256, 0, stream>>>(gs, rdeg, accums, big ? gsb : nullptr);
    if (big) {
        k_hwgemm<true><<<2 * BB, 1024, 0, stream>>>(gs, gsb, hs, W_s, b_s, W_mu, W_lv,
                                                    rdeg, h_ws, vm_ws, vv_ws);
        k_muflow<true><<<4 * BB, 512, 0, stream>>>(gs, gsb, vm_ws, vv_ws, eps, b_mu, b_lv,
                                                   beta, fw, fb, fs, rdeg, zs_ws, zss_ws,
                                                   klp);
        k_dec<true><<<4 * BB, 512, 0, stream>>>(gs, gsb, zss_ws, zs_ws, h_ws, W_dec, b_dec,
                                                msep, xhg);
    } else {
        k_hwgemm<false><<<2 * BB, 1024, 0, stream>>>(gs, gsb, hs, W_s, b_s, W_mu, W_lv,
                                                     rdeg, h_ws, vm_ws, vv_ws);
        k_muflow<false><<<4 * BB, 512, 0, stream>>>(gs, gsb, vm_ws, vv_ws, eps, b_mu, b_lv,
                                                    beta, fw, fb, fs, rdeg, zs_ws, zss_ws,
                                                    klp);
        k_dec<false><<<4 * BB, 512, 0, stream>>>(gs, gsb, zss_ws, zs_ws, h_ws, W_dec, b_dec,
                                                 msep, xhg);
    }
    k_cls<<<BB, 64, 0, stream>>>(xhg, klp, msep, W1, b1, W2, b2, labels, accums, out);
}